// Round 1
// baseline (801.227 us; speedup 1.0000x reference)
//
#include <hip/hip_runtime.h>
#include <hip/hip_bf16.h>

#define B_SZ 16384
#define P_SZ 8
#define D_SZ 512
#define A_SZ 64
#define K1_SZ 576   // D + A
#define H_SZ 1024

typedef __bf16 bf16_t;
typedef __bf16 bf16x8_t __attribute__((ext_vector_type(8)));
typedef float f32x4_t __attribute__((ext_vector_type(4)));

// ---------------- sort prep ----------------

__global__ void hist_kernel(const int* __restrict__ pol, int* __restrict__ counts,
                            int* __restrict__ offsets, int* __restrict__ cursors) {
    __shared__ int lc[P_SZ];
    int t = threadIdx.x;
    if (t < P_SZ) lc[t] = 0;
    __syncthreads();
    for (int i = t; i < B_SZ; i += blockDim.x)
        atomicAdd(&lc[pol[i]], 1);
    __syncthreads();
    if (t == 0) {
        int run = 0;
        for (int p = 0; p < P_SZ; ++p) {
            int c = lc[p];
            counts[p] = c; offsets[p] = run; cursors[p] = run; run += c;
        }
    }
}

__global__ void scatter_kernel(const int* __restrict__ pol, int* __restrict__ cursors,
                               int* __restrict__ rowidx) {
    int i = blockIdx.x * blockDim.x + threadIdx.x;
    if (i < B_SZ) {
        int p = pol[i];
        int pos = atomicAdd(&cursors[p], 1);
        rowidx[pos] = i;
    }
}

// ---------------- GEMM1: h = relu(x @ W1[p] + b1[p]), x = [latents|actions] ----------------
// Block: 256 threads, 4 waves, tile 128(M) x 128(N) x 32(K). Wave = 64x64 via 4x4 of 16x16x32 MFMA.

__global__ __launch_bounds__(256) void gemm1_kernel(
    const float* __restrict__ latents, const float* __restrict__ actions,
    const float* __restrict__ W1, const float* __restrict__ b1,
    const int* __restrict__ counts, const int* __restrict__ offsets,
    const int* __restrict__ rowidx, bf16_t* __restrict__ h) {

    const int p = blockIdx.z;
    const int cnt = counts[p];
    const int m0 = blockIdx.x * 128;
    if (m0 >= cnt) return;
    const int off = offsets[p];
    const int n0 = blockIdx.y * 128;

    __shared__ __align__(16) bf16_t As[128][32];   // [m][k]
    __shared__ __align__(16) bf16_t Bs[128][32];   // [n][k] (transposed on stage)
    __shared__ int rows_s[128];

    const int tid = threadIdx.x;
    if (tid < 128)
        rows_s[tid] = (m0 + tid < cnt) ? rowidx[off + m0 + tid] : -1;
    __syncthreads();

    f32x4_t acc[4][4];
#pragma unroll
    for (int i = 0; i < 4; ++i)
#pragma unroll
        for (int j = 0; j < 4; ++j)
            acc[i][j] = (f32x4_t){0.f, 0.f, 0.f, 0.f};

    const int wave = tid >> 6, lane = tid & 63;
    const int wm = (wave >> 1) * 64, wn = (wave & 1) * 64;
    const int l16 = lane & 15, qd = lane >> 4;

    for (int kt = 0; kt < K1_SZ; kt += 32) {
        // stage A: gathered x rows, fp32 -> bf16. 128x32 elems, 4 float4 per thread.
#pragma unroll
        for (int jj = 0; jj < 4; ++jj) {
            int c = jj * 256 + tid;        // 0..1023
            int r = c >> 3;                // row 0..127
            int cc = (c & 7) << 2;         // col 0..28
            int g = rows_s[r];
            float4 v = make_float4(0.f, 0.f, 0.f, 0.f);
            if (g >= 0) {
                int k = kt + cc;           // tile never straddles k=512 (32 | 512)
                if (k < D_SZ) v = *(const float4*)(latents + (size_t)g * D_SZ + k);
                else          v = *(const float4*)(actions + (size_t)g * A_SZ + (k - D_SZ));
            }
            bf16_t* dst = &As[r][cc];
            dst[0] = (bf16_t)v.x; dst[1] = (bf16_t)v.y;
            dst[2] = (bf16_t)v.z; dst[3] = (bf16_t)v.w;
        }
        // stage B: W1[p] slab [kt..kt+32) x [n0..n0+128), transpose to [n][k]
#pragma unroll
        for (int jj = 0; jj < 4; ++jj) {
            int c = jj * 256 + tid;
            int kk = c >> 5;               // 0..31
            int nn = (c & 31) << 2;        // 0..124
            const float* wp = W1 + ((size_t)p * K1_SZ + kt + kk) * H_SZ + n0 + nn;
            float4 w = *(const float4*)wp;
            Bs[nn + 0][kk] = (bf16_t)w.x;
            Bs[nn + 1][kk] = (bf16_t)w.y;
            Bs[nn + 2][kk] = (bf16_t)w.z;
            Bs[nn + 3][kk] = (bf16_t)w.w;
        }
        __syncthreads();

        bf16x8_t af[4], bfr[4];
#pragma unroll
        for (int i = 0; i < 4; ++i)
            af[i] = *(const bf16x8_t*)&As[wm + i * 16 + l16][qd * 8];
#pragma unroll
        for (int j = 0; j < 4; ++j)
            bfr[j] = *(const bf16x8_t*)&Bs[wn + j * 16 + l16][qd * 8];
#pragma unroll
        for (int i = 0; i < 4; ++i)
#pragma unroll
            for (int j = 0; j < 4; ++j)
                acc[i][j] = __builtin_amdgcn_mfma_f32_16x16x32_bf16(af[i], bfr[j], acc[i][j], 0, 0, 0);
        __syncthreads();
    }

    // epilogue: bias + relu -> h (bf16, sorted row order)
#pragma unroll
    for (int i = 0; i < 4; ++i) {
#pragma unroll
        for (int r = 0; r < 4; ++r) {
            int ml = wm + i * 16 + qd * 4 + r;   // C/D: row = quad*4 + reg
            if (m0 + ml < cnt) {
                size_t row = (size_t)(off + m0 + ml);
#pragma unroll
                for (int j = 0; j < 4; ++j) {
                    int n = n0 + wn + j * 16 + l16; // C/D: col = lane&15
                    float v = acc[i][j][r] + b1[p * H_SZ + n];
                    v = fmaxf(v, 0.f);
                    h[row * H_SZ + n] = (bf16_t)v;
                }
            }
        }
    }
}

// ---------------- GEMM2: out[g] = h_sorted @ W2[p] + b2[p] ----------------

__global__ __launch_bounds__(256) void gemm2_kernel(
    const bf16_t* __restrict__ h, const float* __restrict__ W2,
    const float* __restrict__ b2,
    const int* __restrict__ counts, const int* __restrict__ offsets,
    const int* __restrict__ rowidx, float* __restrict__ out) {

    const int p = blockIdx.z;
    const int cnt = counts[p];
    const int m0 = blockIdx.x * 128;
    if (m0 >= cnt) return;
    const int off = offsets[p];
    const int n0 = blockIdx.y * 128;

    __shared__ __align__(16) bf16_t As[128][32];
    __shared__ __align__(16) bf16_t Bs[128][32];
    __shared__ int rows_s[128];

    const int tid = threadIdx.x;
    if (tid < 128)
        rows_s[tid] = (m0 + tid < cnt) ? rowidx[off + m0 + tid] : -1;
    __syncthreads();

    f32x4_t acc[4][4];
#pragma unroll
    for (int i = 0; i < 4; ++i)
#pragma unroll
        for (int j = 0; j < 4; ++j)
            acc[i][j] = (f32x4_t){0.f, 0.f, 0.f, 0.f};

    const int wave = tid >> 6, lane = tid & 63;
    const int wm = (wave >> 1) * 64, wn = (wave & 1) * 64;
    const int l16 = lane & 15, qd = lane >> 4;

    for (int kt = 0; kt < H_SZ; kt += 32) {
        // stage A from h (already bf16): 128x32 = 512 x 16B chunks, 2 per thread
#pragma unroll
        for (int jj = 0; jj < 2; ++jj) {
            int c = jj * 256 + tid;    // 0..511
            int r = c >> 2;            // row 0..127
            int cc = (c & 3) << 3;     // 0,8,16,24
            int srow = off + m0 + r;
            if (srow >= B_SZ) srow = B_SZ - 1;  // ghost rows: any valid data, store-masked
            *(uint4*)&As[r][cc] = *(const uint4*)(h + (size_t)srow * H_SZ + kt + cc);
        }
        // stage B: W2[p] slab, transpose to [n][k]
#pragma unroll
        for (int jj = 0; jj < 4; ++jj) {
            int c = jj * 256 + tid;
            int kk = c >> 5;
            int nn = (c & 31) << 2;
            const float* wp = W2 + ((size_t)p * H_SZ + kt + kk) * D_SZ + n0 + nn;
            float4 w = *(const float4*)wp;
            Bs[nn + 0][kk] = (bf16_t)w.x;
            Bs[nn + 1][kk] = (bf16_t)w.y;
            Bs[nn + 2][kk] = (bf16_t)w.z;
            Bs[nn + 3][kk] = (bf16_t)w.w;
        }
        __syncthreads();

        bf16x8_t af[4], bfr[4];
#pragma unroll
        for (int i = 0; i < 4; ++i)
            af[i] = *(const bf16x8_t*)&As[wm + i * 16 + l16][qd * 8];
#pragma unroll
        for (int j = 0; j < 4; ++j)
            bfr[j] = *(const bf16x8_t*)&Bs[wn + j * 16 + l16][qd * 8];
#pragma unroll
        for (int i = 0; i < 4; ++i)
#pragma unroll
            for (int j = 0; j < 4; ++j)
                acc[i][j] = __builtin_amdgcn_mfma_f32_16x16x32_bf16(af[i], bfr[j], acc[i][j], 0, 0, 0);
        __syncthreads();
    }

    // epilogue: bias, scatter to original row
#pragma unroll
    for (int i = 0; i < 4; ++i) {
#pragma unroll
        for (int r = 0; r < 4; ++r) {
            int ml = wm + i * 16 + qd * 4 + r;
            if (m0 + ml < cnt) {
                int g = rows_s[ml];
                size_t orow = (size_t)g * D_SZ;
#pragma unroll
                for (int j = 0; j < 4; ++j) {
                    int n = n0 + wn + j * 16 + l16;
                    out[orow + n] = acc[i][j][r] + b2[p * D_SZ + n];
                }
            }
        }
    }
}

// ---------------- launch ----------------

extern "C" void kernel_launch(void* const* d_in, const int* in_sizes, int n_in,
                              void* d_out, int out_size, void* d_ws, size_t ws_size,
                              hipStream_t stream) {
    const float* latents = (const float*)d_in[0];
    const float* actions = (const float*)d_in[1];
    const int*   pol     = (const int*)d_in[2];
    const float* W1      = (const float*)d_in[3];
    const float* b1      = (const float*)d_in[4];
    const float* W2      = (const float*)d_in[5];
    const float* b2      = (const float*)d_in[6];
    float* out = (float*)d_out;

    char* ws = (char*)d_ws;
    int* counts  = (int*)ws;
    int* offsets = counts + P_SZ;
    int* cursors = offsets + P_SZ;
    int* rowidx  = cursors + P_SZ;
    // h region: 256B-aligned after the int block; B*H bf16 = 33.5 MB
    size_t int_bytes = (size_t)(3 * P_SZ + B_SZ) * sizeof(int);
    size_t h_off = (int_bytes + 255) & ~(size_t)255;
    bf16_t* h = (bf16_t*)(ws + h_off);

    hist_kernel<<<1, 1024, 0, stream>>>(pol, counts, offsets, cursors);
    scatter_kernel<<<B_SZ / 256, 256, 0, stream>>>(pol, cursors, rowidx);
    gemm1_kernel<<<dim3(B_SZ / 128, H_SZ / 128, P_SZ), 256, 0, stream>>>(
        latents, actions, W1, b1, counts, offsets, rowidx, h);
    gemm2_kernel<<<dim3(B_SZ / 128, D_SZ / 128, P_SZ), 256, 0, stream>>>(
        h, W2, b2, counts, offsets, rowidx, out);
}

// Round 2
// 307.090 us; speedup vs baseline: 2.6091x; 2.6091x over previous
//
#include <hip/hip_runtime.h>
#include <hip/hip_bf16.h>
#include <stdint.h>

#define B_SZ 16384
#define P_SZ 8
#define D_SZ 512
#define A_SZ 64
#define K1 576    // D + A
#define H_SZ 1024
#define PAD_ROWS 128

typedef __bf16 bf16_t;
typedef __bf16 bf16x8 __attribute__((ext_vector_type(8)));
typedef float f32x4 __attribute__((ext_vector_type(4)));

__device__ __forceinline__ void glds16(const void* g, void* l) {
    __builtin_amdgcn_global_load_lds(
        (const __attribute__((address_space(1))) unsigned*)g,
        (__attribute__((address_space(3))) unsigned*)l, 16, 0, 0);
}

// ---------------- sort prep ----------------

__global__ void hist_kernel(const int* __restrict__ pol, int* __restrict__ counts,
                            int* __restrict__ offsets, int* __restrict__ cursors) {
    __shared__ int lc[P_SZ];
    int t = threadIdx.x;
    if (t < P_SZ) lc[t] = 0;
    __syncthreads();
    for (int i = t; i < B_SZ; i += blockDim.x)
        atomicAdd(&lc[pol[i]], 1);
    __syncthreads();
    if (t == 0) {
        int run = 0;
        for (int p = 0; p < P_SZ; ++p) {
            int c = lc[p];
            counts[p] = c; offsets[p] = run; cursors[p] = run; run += c;
        }
    }
}

__global__ void scatter_kernel(const int* __restrict__ pol, int* __restrict__ cursors,
                               int* __restrict__ rowidx) {
    int i = blockIdx.x * blockDim.x + threadIdx.x;
    if (i < B_SZ) {
        int p = pol[i];
        int pos = atomicAdd(&cursors[p], 1);
        rowidx[pos] = i;
    }
}

// ---------------- prep_x: gather + concat + fp32->bf16, sorted order ----------------
// xs[s][0..575] = bf16([latents[g] | actions[g]]), g = rowidx[s]. One 16B chunk/thread.

__global__ __launch_bounds__(256) void prep_x(const float* __restrict__ latents,
                                              const float* __restrict__ actions,
                                              const int* __restrict__ rowidx,
                                              bf16_t* __restrict__ xs) {
    int idx = blockIdx.x * 256 + threadIdx.x;   // 0 .. 16384*72-1
    int s = idx / 72;
    int c8 = idx - s * 72;
    int col = c8 * 8;
    int g = rowidx[s];
    const float* src;
    if (col < D_SZ) src = latents + (size_t)g * D_SZ + col;
    else            src = actions + (size_t)g * A_SZ + (col - D_SZ);
    f32x4 v0 = *(const f32x4*)src;
    f32x4 v1 = *(const f32x4*)(src + 4);
    bf16x8 o;
    o[0] = (bf16_t)v0[0]; o[1] = (bf16_t)v0[1]; o[2] = (bf16_t)v0[2]; o[3] = (bf16_t)v0[3];
    o[4] = (bf16_t)v1[0]; o[5] = (bf16_t)v1[1]; o[6] = (bf16_t)v1[2]; o[7] = (bf16_t)v1[3];
    *(bf16x8*)(xs + (size_t)s * K1 + col) = o;
}

// ---------------- transpose_w: [P][K][N] f32 -> [P][N][K] bf16 ----------------

__global__ __launch_bounds__(256) void transpose_w(const float* __restrict__ W,
                                                   bf16_t* __restrict__ WT,
                                                   int K, int N) {
    int k0 = blockIdx.x * 32, n0 = blockIdx.y * 32, p = blockIdx.z;
    __shared__ float ls[32][33];
    const float* Wp = W + (size_t)p * K * N;
    bf16_t* WTp = WT + (size_t)p * N * K;
    int tid = threadIdx.x;
#pragma unroll
    for (int e = 0; e < 4; ++e) {
        int idx = e * 256 + tid;
        int kk = idx >> 5, nn = idx & 31;
        ls[kk][nn] = Wp[(size_t)(k0 + kk) * N + n0 + nn];
    }
    __syncthreads();
#pragma unroll
    for (int e = 0; e < 2; ++e) {
        int idx = e * 256 + tid;         // 0..511 pairs
        int nn = idx >> 4, kp = (idx & 15) * 2;
        union { bf16_t h[2]; unsigned u; } pk;
        pk.h[0] = (bf16_t)ls[kp][nn];
        pk.h[1] = (bf16_t)ls[kp + 1][nn];
        *(unsigned*)&WTp[(size_t)(n0 + nn) * K + k0 + kp] = pk.u;
    }
}

// ---------------- GEMM core (m97-style): 128x128x32 tile, glds staging, XOR swizzle ----
// LDS layout: tile[128 rows][4 chunks of 16B]; chunk at stored pos kc holds logical
// chunk kc ^ ((row>>1)&3). glds dest is lane-contiguous; frag reads are 2-way (free).

__global__ __launch_bounds__(256) void gemm1_kernel(
    const bf16_t* __restrict__ xs, const bf16_t* __restrict__ w1t,
    const float* __restrict__ b1,
    const int* __restrict__ counts, const int* __restrict__ offsets,
    bf16_t* __restrict__ h) {

    const int p = blockIdx.z;
    const int cnt = counts[p];
    const int m0 = blockIdx.x * 128;
    if (m0 >= cnt) return;
    const int off = offsets[p];
    const int n0 = blockIdx.y * 128;

    __shared__ __align__(16) bf16_t As[128 * 32];
    __shared__ __align__(16) bf16_t Bs[128 * 32];

    const int tid = threadIdx.x;
    const int wave = tid >> 6, lane = tid & 63;

    // staging: chunk c = wave*128 + i*64 + lane; row=c>>2; load logical chunk (c&3)^((row>>1)&3)
    const int c0 = wave * 128 + lane, c1 = c0 + 64;
    const int r0 = c0 >> 2, r1 = c1 >> 2;
    const int kl0 = (c0 & 3) ^ ((r0 >> 1) & 3);
    const int kl1 = (c1 & 3) ^ ((r1 >> 1) & 3);
    const bf16_t* a_src0 = xs + (size_t)(off + m0 + r0) * K1 + kl0 * 8;
    const bf16_t* a_src1 = xs + (size_t)(off + m0 + r1) * K1 + kl1 * 8;
    const bf16_t* b_src0 = w1t + ((size_t)p * H_SZ + n0 + r0) * K1 + kl0 * 8;
    const bf16_t* b_src1 = w1t + ((size_t)p * H_SZ + n0 + r1) * K1 + kl1 * 8;
    bf16_t* a_dst0 = As + wave * 1024;           // (wave*2+0)*64 chunks * 8 bf16
    bf16_t* a_dst1 = As + wave * 1024 + 512;
    bf16_t* b_dst0 = Bs + wave * 1024;
    bf16_t* b_dst1 = Bs + wave * 1024 + 512;

    const int wm = (wave >> 1) * 64, wn = (wave & 1) * 64;
    const int l16 = lane & 15, qd = lane >> 4;
    const int swz = (l16 >> 1) & 3;
    int aoff[4], boff[4];
#pragma unroll
    for (int i = 0; i < 4; ++i) aoff[i] = (wm + i * 16 + l16) * 32 + ((qd ^ swz) * 8);
#pragma unroll
    for (int j = 0; j < 4; ++j) boff[j] = (wn + j * 16 + l16) * 32 + ((qd ^ swz) * 8);

    f32x4 acc[4][4];
#pragma unroll
    for (int i = 0; i < 4; ++i)
#pragma unroll
        for (int j = 0; j < 4; ++j)
            acc[i][j] = (f32x4){0.f, 0.f, 0.f, 0.f};

    for (int kt = 0; kt < K1; kt += 32) {
        glds16(a_src0 + kt, a_dst0);
        glds16(a_src1 + kt, a_dst1);
        glds16(b_src0 + kt, b_dst0);
        glds16(b_src1 + kt, b_dst1);
        __syncthreads();
        bf16x8 af[4], bfv[4];
#pragma unroll
        for (int i = 0; i < 4; ++i) af[i] = *(const bf16x8*)(As + aoff[i]);
#pragma unroll
        for (int j = 0; j < 4; ++j) bfv[j] = *(const bf16x8*)(Bs + boff[j]);
#pragma unroll
        for (int i = 0; i < 4; ++i)
#pragma unroll
            for (int j = 0; j < 4; ++j)
                acc[i][j] = __builtin_amdgcn_mfma_f32_16x16x32_bf16(af[i], bfv[j], acc[i][j], 0, 0, 0);
        __syncthreads();
    }

    // epilogue: bias + relu -> h (bf16, sorted order)
#pragma unroll
    for (int i = 0; i < 4; ++i) {
#pragma unroll
        for (int r = 0; r < 4; ++r) {
            int ml = wm + i * 16 + qd * 4 + r;   // C/D: row = quad*4 + reg
            if (m0 + ml < cnt) {
                size_t row = (size_t)(off + m0 + ml);
#pragma unroll
                for (int j = 0; j < 4; ++j) {
                    int n = n0 + wn + j * 16 + l16; // C/D: col = lane&15
                    float v = acc[i][j][r] + b1[p * H_SZ + n];
                    h[row * H_SZ + n] = (bf16_t)fmaxf(v, 0.f);
                }
            }
        }
    }
}

__global__ __launch_bounds__(256) void gemm2_kernel(
    const bf16_t* __restrict__ h, const bf16_t* __restrict__ w2t,
    const float* __restrict__ b2,
    const int* __restrict__ counts, const int* __restrict__ offsets,
    const int* __restrict__ rowidx, float* __restrict__ out) {

    const int p = blockIdx.z;
    const int cnt = counts[p];
    const int m0 = blockIdx.x * 128;
    if (m0 >= cnt) return;
    const int off = offsets[p];
    const int n0 = blockIdx.y * 128;

    __shared__ __align__(16) bf16_t As[128 * 32];
    __shared__ __align__(16) bf16_t Bs[128 * 32];
    __shared__ int rows_s[128];

    const int tid = threadIdx.x;
    if (tid < 128)
        rows_s[tid] = (m0 + tid < cnt) ? rowidx[off + m0 + tid] : 0;

    const int wave = tid >> 6, lane = tid & 63;
    const int c0 = wave * 128 + lane, c1 = c0 + 64;
    const int r0 = c0 >> 2, r1 = c1 >> 2;
    const int kl0 = (c0 & 3) ^ ((r0 >> 1) & 3);
    const int kl1 = (c1 & 3) ^ ((r1 >> 1) & 3);
    const bf16_t* a_src0 = h + (size_t)(off + m0 + r0) * H_SZ + kl0 * 8;
    const bf16_t* a_src1 = h + (size_t)(off + m0 + r1) * H_SZ + kl1 * 8;
    const bf16_t* b_src0 = w2t + ((size_t)p * D_SZ + n0 + r0) * H_SZ + kl0 * 8;
    const bf16_t* b_src1 = w2t + ((size_t)p * D_SZ + n0 + r1) * H_SZ + kl1 * 8;
    bf16_t* a_dst0 = As + wave * 1024;
    bf16_t* a_dst1 = As + wave * 1024 + 512;
    bf16_t* b_dst0 = Bs + wave * 1024;
    bf16_t* b_dst1 = Bs + wave * 1024 + 512;

    const int wm = (wave >> 1) * 64, wn = (wave & 1) * 64;
    const int l16 = lane & 15, qd = lane >> 4;
    const int swz = (l16 >> 1) & 3;
    int aoff[4], boff[4];
#pragma unroll
    for (int i = 0; i < 4; ++i) aoff[i] = (wm + i * 16 + l16) * 32 + ((qd ^ swz) * 8);
#pragma unroll
    for (int j = 0; j < 4; ++j) boff[j] = (wn + j * 16 + l16) * 32 + ((qd ^ swz) * 8);

    f32x4 acc[4][4];
#pragma unroll
    for (int i = 0; i < 4; ++i)
#pragma unroll
        for (int j = 0; j < 4; ++j)
            acc[i][j] = (f32x4){0.f, 0.f, 0.f, 0.f};

    for (int kt = 0; kt < H_SZ; kt += 32) {
        glds16(a_src0 + kt, a_dst0);
        glds16(a_src1 + kt, a_dst1);
        glds16(b_src0 + kt, b_dst0);
        glds16(b_src1 + kt, b_dst1);
        __syncthreads();
        bf16x8 af[4], bfv[4];
#pragma unroll
        for (int i = 0; i < 4; ++i) af[i] = *(const bf16x8*)(As + aoff[i]);
#pragma unroll
        for (int j = 0; j < 4; ++j) bfv[j] = *(const bf16x8*)(Bs + boff[j]);
#pragma unroll
        for (int i = 0; i < 4; ++i)
#pragma unroll
            for (int j = 0; j < 4; ++j)
                acc[i][j] = __builtin_amdgcn_mfma_f32_16x16x32_bf16(af[i], bfv[j], acc[i][j], 0, 0, 0);
        __syncthreads();
    }

    // epilogue: bias, scatter to original rows
#pragma unroll
    for (int i = 0; i < 4; ++i) {
#pragma unroll
        for (int r = 0; r < 4; ++r) {
            int ml = wm + i * 16 + qd * 4 + r;
            if (m0 + ml < cnt) {
                size_t orow = (size_t)rows_s[ml] * D_SZ;
#pragma unroll
                for (int j = 0; j < 4; ++j) {
                    int n = n0 + wn + j * 16 + l16;
                    out[orow + n] = acc[i][j][r] + b2[p * D_SZ + n];
                }
            }
        }
    }
}

// ---------------- launch ----------------

extern "C" void kernel_launch(void* const* d_in, const int* in_sizes, int n_in,
                              void* d_out, int out_size, void* d_ws, size_t ws_size,
                              hipStream_t stream) {
    const float* latents = (const float*)d_in[0];
    const float* actions = (const float*)d_in[1];
    const int*   pol     = (const int*)d_in[2];
    const float* W1      = (const float*)d_in[3];
    const float* b1      = (const float*)d_in[4];
    const float* W2      = (const float*)d_in[5];
    const float* b2      = (const float*)d_in[6];
    float* out = (float*)d_out;

    char* ws = (char*)d_ws;
    int* counts  = (int*)ws;
    int* offsets = counts + P_SZ;
    int* cursors = offsets + P_SZ;
    int* rowidx  = cursors + P_SZ;
    size_t pos = ((size_t)(3 * P_SZ + B_SZ) * sizeof(int) + 255) & ~(size_t)255;
    bf16_t* xs  = (bf16_t*)(ws + pos);  pos += (size_t)(B_SZ + PAD_ROWS) * K1 * 2;
    bf16_t* hbuf= (bf16_t*)(ws + pos);  pos += (size_t)(B_SZ + PAD_ROWS) * H_SZ * 2;
    bf16_t* w1t = (bf16_t*)(ws + pos);  pos += (size_t)P_SZ * H_SZ * K1 * 2;
    bf16_t* w2t = (bf16_t*)(ws + pos);  pos += (size_t)P_SZ * D_SZ * H_SZ * 2;

    hist_kernel<<<1, 1024, 0, stream>>>(pol, counts, offsets, cursors);
    scatter_kernel<<<B_SZ / 256, 256, 0, stream>>>(pol, cursors, rowidx);
    prep_x<<<(B_SZ * 72) / 256, 256, 0, stream>>>(latents, actions, rowidx, xs);
    transpose_w<<<dim3(K1 / 32, H_SZ / 32, P_SZ), 256, 0, stream>>>(W1, w1t, K1, H_SZ);
    transpose_w<<<dim3(H_SZ / 32, D_SZ / 32, P_SZ), 256, 0, stream>>>(W2, w2t, H_SZ, D_SZ);
    gemm1_kernel<<<dim3(B_SZ / 128, H_SZ / 128, P_SZ), 256, 0, stream>>>(
        xs, w1t, b1, counts, offsets, hbuf);
    gemm2_kernel<<<dim3(B_SZ / 128, D_SZ / 128, P_SZ), 256, 0, stream>>>(
        hbuf, w2t, b2, counts, offsets, rowidx, out);
}

// Round 3
// 242.775 us; speedup vs baseline: 3.3003x; 1.2649x over previous
//
#include <hip/hip_runtime.h>
#include <hip/hip_bf16.h>
#include <stdint.h>

#define B_SZ 16384
#define P_SZ 8
#define D_SZ 512
#define A_SZ 64
#define K1 576    // D + A
#define H_SZ 1024
#define PAD_ROWS 128
#define NSEG 64   // histogram/scatter segments

typedef __bf16 bf16_t;
typedef __bf16 bf16x8 __attribute__((ext_vector_type(8)));
typedef float f32x4 __attribute__((ext_vector_type(4)));

__device__ __forceinline__ void glds16(const void* g, void* l) {
    __builtin_amdgcn_global_load_lds(
        (const __attribute__((address_space(1))) unsigned*)g,
        (__attribute__((address_space(3))) unsigned*)l, 16, 0, 0);
}

// ---------------- sort prep (block-aggregated, low atomic contention) ----------------

__global__ __launch_bounds__(256) void hist_block(const int* __restrict__ pol,
                                                  int* __restrict__ blockhist) {
    __shared__ int lc[P_SZ];
    int t = threadIdx.x;
    if (t < P_SZ) lc[t] = 0;
    __syncthreads();
    int i = blockIdx.x * 256 + t;
    atomicAdd(&lc[pol[i]], 1);
    __syncthreads();
    if (t < P_SZ) blockhist[blockIdx.x * P_SZ + t] = lc[t];
}

__global__ __launch_bounds__(64) void prefix_kernel(const int* __restrict__ blockhist,
                                                    int* __restrict__ counts,
                                                    int* __restrict__ offsets,
                                                    int* __restrict__ cursors) {
    int t = threadIdx.x;
    if (t < P_SZ) {
        int s = 0;
        for (int b = 0; b < NSEG; ++b) s += blockhist[b * P_SZ + t];
        counts[t] = s;
    }
    __syncthreads();
    if (t == 0) {
        int run = 0;
        for (int p = 0; p < P_SZ; ++p) {
            offsets[p] = run; cursors[p] = run; run += counts[p];
        }
    }
}

__global__ __launch_bounds__(256) void scatter_agg(const int* __restrict__ pol,
                                                   int* __restrict__ cursors,
                                                   int* __restrict__ rowidx) {
    __shared__ int lc[P_SZ], base_s[P_SZ];
    int t = threadIdx.x;
    if (t < P_SZ) lc[t] = 0;
    __syncthreads();
    int i = blockIdx.x * 256 + t;
    int p = pol[i];
    int lpos = atomicAdd(&lc[p], 1);
    __syncthreads();
    if (t < P_SZ) base_s[t] = atomicAdd(&cursors[t], lc[t]);
    __syncthreads();
    rowidx[base_s[p] + lpos] = i;
}

// ---------------- prep_x: gather + concat + fp32->bf16, sorted order ----------------

__global__ __launch_bounds__(256) void prep_x(const float* __restrict__ latents,
                                              const float* __restrict__ actions,
                                              const int* __restrict__ rowidx,
                                              bf16_t* __restrict__ xs) {
    int idx = blockIdx.x * 256 + threadIdx.x;   // 0 .. 16384*72-1
    int s = idx / 72;
    int c8 = idx - s * 72;
    int col = c8 * 8;
    int g = rowidx[s];
    const float* src;
    if (col < D_SZ) src = latents + (size_t)g * D_SZ + col;
    else            src = actions + (size_t)g * A_SZ + (col - D_SZ);
    f32x4 v0 = *(const f32x4*)src;
    f32x4 v1 = *(const f32x4*)(src + 4);
    bf16x8 o;
    o[0] = (bf16_t)v0[0]; o[1] = (bf16_t)v0[1]; o[2] = (bf16_t)v0[2]; o[3] = (bf16_t)v0[3];
    o[4] = (bf16_t)v1[0]; o[5] = (bf16_t)v1[1]; o[6] = (bf16_t)v1[2]; o[7] = (bf16_t)v1[3];
    *(bf16x8*)(xs + (size_t)s * K1 + col) = o;
}

// ---------------- transpose_w: [P][K][N] f32 -> [P][N][K] bf16 ----------------

__global__ __launch_bounds__(256) void transpose_w(const float* __restrict__ W,
                                                   bf16_t* __restrict__ WT,
                                                   int K, int N) {
    int k0 = blockIdx.x * 32, n0 = blockIdx.y * 32, p = blockIdx.z;
    __shared__ float ls[32][33];
    const float* Wp = W + (size_t)p * K * N;
    bf16_t* WTp = WT + (size_t)p * N * K;
    int tid = threadIdx.x;
#pragma unroll
    for (int e = 0; e < 4; ++e) {
        int idx = e * 256 + tid;
        int kk = idx >> 5, nn = idx & 31;
        ls[kk][nn] = Wp[(size_t)(k0 + kk) * N + n0 + nn];
    }
    __syncthreads();
#pragma unroll
    for (int e = 0; e < 2; ++e) {
        int idx = e * 256 + tid;         // 0..511 pairs
        int nn = idx >> 4, kp = (idx & 15) * 2;
        union { bf16_t h[2]; unsigned u; } pk;
        pk.h[0] = (bf16_t)ls[kp][nn];
        pk.h[1] = (bf16_t)ls[kp + 1][nn];
        *(unsigned*)&WTp[(size_t)(n0 + nn) * K + k0 + kp] = pk.u;
    }
}

// ---------------- GEMM core (m97-style): 128x128x32 tile, glds staging, XOR swizzle ----

__global__ __launch_bounds__(256) void gemm1_kernel(
    const bf16_t* __restrict__ xs, const bf16_t* __restrict__ w1t,
    const float* __restrict__ b1,
    const int* __restrict__ counts, const int* __restrict__ offsets,
    bf16_t* __restrict__ h) {

    const int p = blockIdx.z;
    const int cnt = counts[p];
    const int m0 = blockIdx.x * 128;
    if (m0 >= cnt) return;
    const int off = offsets[p];
    const int n0 = blockIdx.y * 128;

    __shared__ __align__(16) bf16_t As[128 * 32];
    __shared__ __align__(16) bf16_t Bs[128 * 32];

    const int tid = threadIdx.x;
    const int wave = tid >> 6, lane = tid & 63;

    const int c0 = wave * 128 + lane, c1 = c0 + 64;
    const int r0 = c0 >> 2, r1 = c1 >> 2;
    const int kl0 = (c0 & 3) ^ ((r0 >> 1) & 3);
    const int kl1 = (c1 & 3) ^ ((r1 >> 1) & 3);
    const bf16_t* a_src0 = xs + (size_t)(off + m0 + r0) * K1 + kl0 * 8;
    const bf16_t* a_src1 = xs + (size_t)(off + m0 + r1) * K1 + kl1 * 8;
    const bf16_t* b_src0 = w1t + ((size_t)p * H_SZ + n0 + r0) * K1 + kl0 * 8;
    const bf16_t* b_src1 = w1t + ((size_t)p * H_SZ + n0 + r1) * K1 + kl1 * 8;
    bf16_t* a_dst0 = As + wave * 1024;
    bf16_t* a_dst1 = As + wave * 1024 + 512;
    bf16_t* b_dst0 = Bs + wave * 1024;
    bf16_t* b_dst1 = Bs + wave * 1024 + 512;

    const int wm = (wave >> 1) * 64, wn = (wave & 1) * 64;
    const int l16 = lane & 15, qd = lane >> 4;
    const int swz = (l16 >> 1) & 3;
    int aoff[4], boff[4];
#pragma unroll
    for (int i = 0; i < 4; ++i) aoff[i] = (wm + i * 16 + l16) * 32 + ((qd ^ swz) * 8);
#pragma unroll
    for (int j = 0; j < 4; ++j) boff[j] = (wn + j * 16 + l16) * 32 + ((qd ^ swz) * 8);

    f32x4 acc[4][4];
#pragma unroll
    for (int i = 0; i < 4; ++i)
#pragma unroll
        for (int j = 0; j < 4; ++j)
            acc[i][j] = (f32x4){0.f, 0.f, 0.f, 0.f};

    for (int kt = 0; kt < K1; kt += 32) {
        glds16(a_src0 + kt, a_dst0);
        glds16(a_src1 + kt, a_dst1);
        glds16(b_src0 + kt, b_dst0);
        glds16(b_src1 + kt, b_dst1);
        __syncthreads();
        bf16x8 af[4], bfv[4];
#pragma unroll
        for (int i = 0; i < 4; ++i) af[i] = *(const bf16x8*)(As + aoff[i]);
#pragma unroll
        for (int j = 0; j < 4; ++j) bfv[j] = *(const bf16x8*)(Bs + boff[j]);
#pragma unroll
        for (int i = 0; i < 4; ++i)
#pragma unroll
            for (int j = 0; j < 4; ++j)
                acc[i][j] = __builtin_amdgcn_mfma_f32_16x16x32_bf16(af[i], bfv[j], acc[i][j], 0, 0, 0);
        __syncthreads();
    }

#pragma unroll
    for (int i = 0; i < 4; ++i) {
#pragma unroll
        for (int r = 0; r < 4; ++r) {
            int ml = wm + i * 16 + qd * 4 + r;   // C/D: row = quad*4 + reg
            if (m0 + ml < cnt) {
                size_t row = (size_t)(off + m0 + ml);
#pragma unroll
                for (int j = 0; j < 4; ++j) {
                    int n = n0 + wn + j * 16 + l16; // C/D: col = lane&15
                    float v = acc[i][j][r] + b1[p * H_SZ + n];
                    h[row * H_SZ + n] = (bf16_t)fmaxf(v, 0.f);
                }
            }
        }
    }
}

__global__ __launch_bounds__(256) void gemm2_kernel(
    const bf16_t* __restrict__ h, const bf16_t* __restrict__ w2t,
    const float* __restrict__ b2,
    const int* __restrict__ counts, const int* __restrict__ offsets,
    const int* __restrict__ rowidx, float* __restrict__ out) {

    const int p = blockIdx.z;
    const int cnt = counts[p];
    const int m0 = blockIdx.x * 128;
    if (m0 >= cnt) return;
    const int off = offsets[p];
    const int n0 = blockIdx.y * 128;

    __shared__ __align__(16) bf16_t As[128 * 32];
    __shared__ __align__(16) bf16_t Bs[128 * 32];
    __shared__ int rows_s[128];

    const int tid = threadIdx.x;
    if (tid < 128)
        rows_s[tid] = (m0 + tid < cnt) ? rowidx[off + m0 + tid] : 0;

    const int wave = tid >> 6, lane = tid & 63;
    const int c0 = wave * 128 + lane, c1 = c0 + 64;
    const int r0 = c0 >> 2, r1 = c1 >> 2;
    const int kl0 = (c0 & 3) ^ ((r0 >> 1) & 3);
    const int kl1 = (c1 & 3) ^ ((r1 >> 1) & 3);
    const bf16_t* a_src0 = h + (size_t)(off + m0 + r0) * H_SZ + kl0 * 8;
    const bf16_t* a_src1 = h + (size_t)(off + m0 + r1) * H_SZ + kl1 * 8;
    const bf16_t* b_src0 = w2t + ((size_t)p * D_SZ + n0 + r0) * H_SZ + kl0 * 8;
    const bf16_t* b_src1 = w2t + ((size_t)p * D_SZ + n0 + r1) * H_SZ + kl1 * 8;
    bf16_t* a_dst0 = As + wave * 1024;
    bf16_t* a_dst1 = As + wave * 1024 + 512;
    bf16_t* b_dst0 = Bs + wave * 1024;
    bf16_t* b_dst1 = Bs + wave * 1024 + 512;

    const int wm = (wave >> 1) * 64, wn = (wave & 1) * 64;
    const int l16 = lane & 15, qd = lane >> 4;
    const int swz = (l16 >> 1) & 3;
    int aoff[4], boff[4];
#pragma unroll
    for (int i = 0; i < 4; ++i) aoff[i] = (wm + i * 16 + l16) * 32 + ((qd ^ swz) * 8);
#pragma unroll
    for (int j = 0; j < 4; ++j) boff[j] = (wn + j * 16 + l16) * 32 + ((qd ^ swz) * 8);

    f32x4 acc[4][4];
#pragma unroll
    for (int i = 0; i < 4; ++i)
#pragma unroll
        for (int j = 0; j < 4; ++j)
            acc[i][j] = (f32x4){0.f, 0.f, 0.f, 0.f};

    for (int kt = 0; kt < H_SZ; kt += 32) {
        glds16(a_src0 + kt, a_dst0);
        glds16(a_src1 + kt, a_dst1);
        glds16(b_src0 + kt, b_dst0);
        glds16(b_src1 + kt, b_dst1);
        __syncthreads();
        bf16x8 af[4], bfv[4];
#pragma unroll
        for (int i = 0; i < 4; ++i) af[i] = *(const bf16x8*)(As + aoff[i]);
#pragma unroll
        for (int j = 0; j < 4; ++j) bfv[j] = *(const bf16x8*)(Bs + boff[j]);
#pragma unroll
        for (int i = 0; i < 4; ++i)
#pragma unroll
            for (int j = 0; j < 4; ++j)
                acc[i][j] = __builtin_amdgcn_mfma_f32_16x16x32_bf16(af[i], bfv[j], acc[i][j], 0, 0, 0);
        __syncthreads();
    }

#pragma unroll
    for (int i = 0; i < 4; ++i) {
#pragma unroll
        for (int r = 0; r < 4; ++r) {
            int ml = wm + i * 16 + qd * 4 + r;
            if (m0 + ml < cnt) {
                size_t orow = (size_t)rows_s[ml] * D_SZ;
#pragma unroll
                for (int j = 0; j < 4; ++j) {
                    int n = n0 + wn + j * 16 + l16;
                    out[orow + n] = acc[i][j][r] + b2[p * D_SZ + n];
                }
            }
        }
    }
}

// ---------------- launch ----------------

extern "C" void kernel_launch(void* const* d_in, const int* in_sizes, int n_in,
                              void* d_out, int out_size, void* d_ws, size_t ws_size,
                              hipStream_t stream) {
    const float* latents = (const float*)d_in[0];
    const float* actions = (const float*)d_in[1];
    const int*   pol     = (const int*)d_in[2];
    const float* W1      = (const float*)d_in[3];
    const float* b1      = (const float*)d_in[4];
    const float* W2      = (const float*)d_in[5];
    const float* b2      = (const float*)d_in[6];
    float* out = (float*)d_out;

    char* ws = (char*)d_ws;
    int* counts    = (int*)ws;
    int* offsets   = counts + P_SZ;
    int* cursors   = offsets + P_SZ;
    int* blockhist = cursors + P_SZ;           // NSEG * P_SZ
    int* rowidx    = blockhist + NSEG * P_SZ;  // B_SZ
    size_t pos = ((size_t)(3 * P_SZ + NSEG * P_SZ + B_SZ) * sizeof(int) + 255) & ~(size_t)255;
    bf16_t* xs  = (bf16_t*)(ws + pos);  pos += (size_t)(B_SZ + PAD_ROWS) * K1 * 2;
    bf16_t* hbuf= (bf16_t*)(ws + pos);  pos += (size_t)(B_SZ + PAD_ROWS) * H_SZ * 2;
    bf16_t* w1t = (bf16_t*)(ws + pos);  pos += (size_t)P_SZ * H_SZ * K1 * 2;
    bf16_t* w2t = (bf16_t*)(ws + pos);  pos += (size_t)P_SZ * D_SZ * H_SZ * 2;

    hist_block<<<NSEG, 256, 0, stream>>>(pol, blockhist);
    prefix_kernel<<<1, 64, 0, stream>>>(blockhist, counts, offsets, cursors);
    scatter_agg<<<NSEG, 256, 0, stream>>>(pol, cursors, rowidx);
    prep_x<<<(B_SZ * 72) / 256, 256, 0, stream>>>(latents, actions, rowidx, xs);
    transpose_w<<<dim3(K1 / 32, H_SZ / 32, P_SZ), 256, 0, stream>>>(W1, w1t, K1, H_SZ);
    transpose_w<<<dim3(H_SZ / 32, D_SZ / 32, P_SZ), 256, 0, stream>>>(W2, w2t, H_SZ, D_SZ);
    gemm1_kernel<<<dim3(B_SZ / 128, H_SZ / 128, P_SZ), 256, 0, stream>>>(
        xs, w1t, b1, counts, offsets, hbuf);
    gemm2_kernel<<<dim3(B_SZ / 128, D_SZ / 128, P_SZ), 256, 0, stream>>>(
        hbuf, w2t, b2, counts, offsets, rowidx, out);
}

// Round 4
// 229.228 us; speedup vs baseline: 3.4953x; 1.0591x over previous
//
#include <hip/hip_runtime.h>
#include <hip/hip_bf16.h>
#include <stdint.h>

#define B_SZ 16384
#define P_SZ 8
#define D_SZ 512
#define A_SZ 64
#define K1 576    // D + A
#define H_SZ 1024
#define NSEG 64
#define MB_MAX 264              // max 64-row m-blocks after per-policy padding
#define BPAD (B_SZ + P_SZ*64)   // 16896 padded sorted-row capacity

// s_waitcnt imm: vmcnt[3:0]|[15:14], expcnt[6:4], lgkmcnt[11:8]
#define WAIT_VM8 0x0F78   // vmcnt<=8, no exp/lgkm wait
#define WAIT_VM0 0x0F70   // vmcnt==0

typedef __bf16 bf16_t;
typedef __bf16 bf16x8 __attribute__((ext_vector_type(8)));
typedef float f32x4 __attribute__((ext_vector_type(4)));

__device__ __forceinline__ void glds16(const void* g, void* l) {
    __builtin_amdgcn_global_load_lds(
        (const __attribute__((address_space(1))) unsigned*)g,
        (__attribute__((address_space(3))) unsigned*)l, 16, 0, 0);
}

// ---------------- sort prep ----------------

__global__ __launch_bounds__(256) void hist_block(const int* __restrict__ pol,
                                                  int* __restrict__ blockhist,
                                                  int* __restrict__ rowidx) {
    __shared__ int lc[P_SZ];
    int t = threadIdx.x;
    if (t < P_SZ) lc[t] = 0;
    __syncthreads();
    int gid = blockIdx.x * 256 + t;
    rowidx[gid] = -1;                       // init pad slots; scatter overwrites real ones
    if (gid < BPAD - B_SZ) rowidx[B_SZ + gid] = -1;
    atomicAdd(&lc[pol[gid]], 1);
    __syncthreads();
    if (t < P_SZ) blockhist[blockIdx.x * P_SZ + t] = lc[t];
}

__global__ __launch_bounds__(64) void prefix_kernel(const int* __restrict__ blockhist,
                                                    int* __restrict__ counts,
                                                    int* __restrict__ cursors,
                                                    int* __restrict__ blk_p) {
    int t = threadIdx.x;
    if (t < P_SZ) {
        int s = 0;
        for (int b = 0; b < NSEG; ++b) s += blockhist[b * P_SZ + t];
        counts[t] = s;
    }
    __syncthreads();
    if (t == 0) {
        int run = 0;   // padded (64-aligned) running offset
        for (int p = 0; p < P_SZ; ++p) {
            cursors[p] = run;
            int nb = (counts[p] + 63) >> 6;
            for (int b = 0; b < nb; ++b) blk_p[(run >> 6) + b] = p;
            run += nb * 64;
        }
        for (int b = run >> 6; b < MB_MAX; ++b) blk_p[b] = -1;
    }
}

__global__ __launch_bounds__(256) void scatter_agg(const int* __restrict__ pol,
                                                   int* __restrict__ cursors,
                                                   int* __restrict__ rowidx) {
    __shared__ int lc[P_SZ], base_s[P_SZ];
    int t = threadIdx.x;
    if (t < P_SZ) lc[t] = 0;
    __syncthreads();
    int i = blockIdx.x * 256 + t;
    int p = pol[i];
    int lpos = atomicAdd(&lc[p], 1);
    __syncthreads();
    if (t < P_SZ) base_s[t] = atomicAdd(&cursors[t], lc[t]);
    __syncthreads();
    rowidx[base_s[p] + lpos] = i;
}

// ---------------- prep_x: gather + concat + fp32->bf16 into padded sorted layout ----

__global__ __launch_bounds__(256) void prep_x(const float* __restrict__ latents,
                                              const float* __restrict__ actions,
                                              const int* __restrict__ rowidx,
                                              bf16_t* __restrict__ xs) {
    int idx = blockIdx.x * 256 + threadIdx.x;   // 0 .. BPAD*72-1
    int s = idx / 72;
    int col = (idx - s * 72) * 8;
    int g = rowidx[s];
    bf16x8 o;
    if (g < 0) {
        o = (bf16x8){0,0,0,0,0,0,0,0};          // pad rows: zeros
    } else {
        const float* src;
        if (col < D_SZ) src = latents + (size_t)g * D_SZ + col;
        else            src = actions + (size_t)g * A_SZ + (col - D_SZ);
        f32x4 v0 = *(const f32x4*)src;
        f32x4 v1 = *(const f32x4*)(src + 4);
        o[0] = (bf16_t)v0[0]; o[1] = (bf16_t)v0[1]; o[2] = (bf16_t)v0[2]; o[3] = (bf16_t)v0[3];
        o[4] = (bf16_t)v1[0]; o[5] = (bf16_t)v1[1]; o[6] = (bf16_t)v1[2]; o[7] = (bf16_t)v1[3];
    }
    *(bf16x8*)(xs + (size_t)s * K1 + col) = o;
}

// ---------------- transpose_w (merged): [P][K][N] f32 -> [P][N][K] bf16, both weights ----

__global__ __launch_bounds__(256) void transpose_w(const float* __restrict__ W1,
                                                   const float* __restrict__ W2,
                                                   bf16_t* __restrict__ w1t,
                                                   bf16_t* __restrict__ w2t) {
    int z = blockIdx.z;
    int K = (z < P_SZ) ? K1 : H_SZ;
    int N = (z < P_SZ) ? H_SZ : D_SZ;
    int k0 = blockIdx.x * 32, n0 = blockIdx.y * 32;
    if (k0 >= K || n0 >= N) return;
    int p = z & 7;
    const float* Wp = ((z < P_SZ) ? W1 : W2) + (size_t)p * K * N;
    bf16_t* WTp = ((z < P_SZ) ? w1t : w2t) + (size_t)p * N * K;
    __shared__ float ls[32][33];
    int tid = threadIdx.x;
#pragma unroll
    for (int e = 0; e < 4; ++e) {
        int idx = e * 256 + tid;
        int kk = idx >> 5, nn = idx & 31;
        ls[kk][nn] = Wp[(size_t)(k0 + kk) * N + n0 + nn];
    }
    __syncthreads();
#pragma unroll
    for (int e = 0; e < 2; ++e) {
        int idx = e * 256 + tid;
        int nn = idx >> 4, kp = (idx & 15) * 2;
        union { bf16_t h[2]; unsigned u; } pk;
        pk.h[0] = (bf16_t)ls[kp][nn];
        pk.h[1] = (bf16_t)ls[kp + 1][nn];
        *(unsigned*)&WTp[(size_t)(n0 + nn) * K + k0 + kp] = pk.u;
    }
}

// ---------------- barrier-free per-wave GEMMs ----------------
// 1 wave/block computes 64x64. Private LDS double buffer, 2-deep glds pipeline,
// manual s_waitcnt vmcnt(8) instead of __syncthreads -> no vmcnt(0) drain.
// LDS chunk c=i*64+lane stores logical k-chunk (c&3)^((row>>1)&3) (XOR swizzle,
// measured 0 conflicts in round 3's layout).

__global__ __launch_bounds__(64) void gemm1_kernel(
    const bf16_t* __restrict__ xs, const bf16_t* __restrict__ w1t,
    const float* __restrict__ b1, const int* __restrict__ blk_p,
    bf16_t* __restrict__ h) {

    const int p = blk_p[blockIdx.x];
    if (p < 0) return;
    const int m0 = blockIdx.x * 64;
    const int n0 = blockIdx.y * 64;

    __shared__ __align__(16) bf16_t As[2][64 * 32];
    __shared__ __align__(16) bf16_t Bs[2][64 * 32];

    const int lane = threadIdx.x;
    const bf16_t* a_src[4];
    const bf16_t* b_src[4];
    int dstc[4];
#pragma unroll
    for (int i = 0; i < 4; ++i) {
        int c = i * 64 + lane;
        int r = c >> 2;
        int kl = (c & 3) ^ ((r >> 1) & 3);
        a_src[i] = xs + (size_t)(m0 + r) * K1 + kl * 8;
        b_src[i] = w1t + ((size_t)p * H_SZ + n0 + r) * K1 + kl * 8;
        dstc[i] = c * 8;
    }

    const int l16 = lane & 15, qd = lane >> 4;
    const int swz = (l16 >> 1) & 3;
    int aoff[4], boff[4];
#pragma unroll
    for (int i = 0; i < 4; ++i) aoff[i] = (i * 16 + l16) * 32 + ((qd ^ swz) * 8);
#pragma unroll
    for (int j = 0; j < 4; ++j) boff[j] = (j * 16 + l16) * 32 + ((qd ^ swz) * 8);

    f32x4 acc[4][4];
#pragma unroll
    for (int i = 0; i < 4; ++i)
#pragma unroll
        for (int j = 0; j < 4; ++j)
            acc[i][j] = (f32x4){0.f, 0.f, 0.f, 0.f};

    const int NK = K1 / 32;   // 18
    // prologue: k=0 into buf 0
#pragma unroll
    for (int i = 0; i < 4; ++i) glds16(a_src[i], &As[0][dstc[i]]);
#pragma unroll
    for (int i = 0; i < 4; ++i) glds16(b_src[i], &Bs[0][dstc[i]]);

    for (int k = 0; k < NK; ++k) {
        const int cur = k & 1;
        if (k + 1 < NK) {
            const int kt = (k + 1) * 32;
            const int nxt = cur ^ 1;
#pragma unroll
            for (int i = 0; i < 4; ++i) glds16(a_src[i] + kt, &As[nxt][dstc[i]]);
#pragma unroll
            for (int i = 0; i < 4; ++i) glds16(b_src[i] + kt, &Bs[nxt][dstc[i]]);
            __builtin_amdgcn_s_waitcnt(WAIT_VM8);   // iter k's 8 loads landed
        } else {
            __builtin_amdgcn_s_waitcnt(WAIT_VM0);
        }
        __builtin_amdgcn_sched_barrier(0);          // pin ds_reads behind the waitcnt
        bf16x8 af[4], bfv[4];
#pragma unroll
        for (int i = 0; i < 4; ++i) af[i] = *(const bf16x8*)(&As[cur][aoff[i]]);
#pragma unroll
        for (int j = 0; j < 4; ++j) bfv[j] = *(const bf16x8*)(&Bs[cur][boff[j]]);
#pragma unroll
        for (int i = 0; i < 4; ++i)
#pragma unroll
            for (int j = 0; j < 4; ++j)
                acc[i][j] = __builtin_amdgcn_mfma_f32_16x16x32_bf16(af[i], bfv[j], acc[i][j], 0, 0, 0);
    }

    // epilogue: bias + relu -> h (padded sorted layout, pad rows written harmlessly)
#pragma unroll
    for (int i = 0; i < 4; ++i) {
#pragma unroll
        for (int r = 0; r < 4; ++r) {
            int ml = i * 16 + qd * 4 + r;      // C/D: row = quad*4 + reg
            size_t row = (size_t)(m0 + ml);
#pragma unroll
            for (int j = 0; j < 4; ++j) {
                int n = n0 + j * 16 + l16;     // C/D: col = lane&15
                float v = acc[i][j][r] + b1[p * H_SZ + n];
                h[row * H_SZ + n] = (bf16_t)fmaxf(v, 0.f);
            }
        }
    }
}

__global__ __launch_bounds__(64) void gemm2_kernel(
    const bf16_t* __restrict__ h, const bf16_t* __restrict__ w2t,
    const float* __restrict__ b2, const int* __restrict__ blk_p,
    const int* __restrict__ rowidx, float* __restrict__ out) {

    const int p = blk_p[blockIdx.x];
    if (p < 0) return;
    const int m0 = blockIdx.x * 64;
    const int n0 = blockIdx.y * 64;

    __shared__ __align__(16) bf16_t As[2][64 * 32];
    __shared__ __align__(16) bf16_t Bs[2][64 * 32];

    const int lane = threadIdx.x;
    const bf16_t* a_src[4];
    const bf16_t* b_src[4];
    int dstc[4];
#pragma unroll
    for (int i = 0; i < 4; ++i) {
        int c = i * 64 + lane;
        int r = c >> 2;
        int kl = (c & 3) ^ ((r >> 1) & 3);
        a_src[i] = h + (size_t)(m0 + r) * H_SZ + kl * 8;
        b_src[i] = w2t + ((size_t)p * D_SZ + n0 + r) * H_SZ + kl * 8;
        dstc[i] = c * 8;
    }

    const int l16 = lane & 15, qd = lane >> 4;
    const int swz = (l16 >> 1) & 3;
    int aoff[4], boff[4];
#pragma unroll
    for (int i = 0; i < 4; ++i) aoff[i] = (i * 16 + l16) * 32 + ((qd ^ swz) * 8);
#pragma unroll
    for (int j = 0; j < 4; ++j) boff[j] = (j * 16 + l16) * 32 + ((qd ^ swz) * 8);

    f32x4 acc[4][4];
#pragma unroll
    for (int i = 0; i < 4; ++i)
#pragma unroll
        for (int j = 0; j < 4; ++j)
            acc[i][j] = (f32x4){0.f, 0.f, 0.f, 0.f};

    const int NK = H_SZ / 32;   // 32
#pragma unroll
    for (int i = 0; i < 4; ++i) glds16(a_src[i], &As[0][dstc[i]]);
#pragma unroll
    for (int i = 0; i < 4; ++i) glds16(b_src[i], &Bs[0][dstc[i]]);

    for (int k = 0; k < NK; ++k) {
        const int cur = k & 1;
        if (k + 1 < NK) {
            const int kt = (k + 1) * 32;
            const int nxt = cur ^ 1;
#pragma unroll
            for (int i = 0; i < 4; ++i) glds16(a_src[i] + kt, &As[nxt][dstc[i]]);
#pragma unroll
            for (int i = 0; i < 4; ++i) glds16(b_src[i] + kt, &Bs[nxt][dstc[i]]);
            __builtin_amdgcn_s_waitcnt(WAIT_VM8);
        } else {
            __builtin_amdgcn_s_waitcnt(WAIT_VM0);
        }
        __builtin_amdgcn_sched_barrier(0);
        bf16x8 af[4], bfv[4];
#pragma unroll
        for (int i = 0; i < 4; ++i) af[i] = *(const bf16x8*)(&As[cur][aoff[i]]);
#pragma unroll
        for (int j = 0; j < 4; ++j) bfv[j] = *(const bf16x8*)(&Bs[cur][boff[j]]);
#pragma unroll
        for (int i = 0; i < 4; ++i)
#pragma unroll
            for (int j = 0; j < 4; ++j)
                acc[i][j] = __builtin_amdgcn_mfma_f32_16x16x32_bf16(af[i], bfv[j], acc[i][j], 0, 0, 0);
    }

    // epilogue: bias, scatter to original rows; pad rows (rowidx<0) masked
#pragma unroll
    for (int i = 0; i < 4; ++i) {
#pragma unroll
        for (int r = 0; r < 4; ++r) {
            int ml = i * 16 + qd * 4 + r;
            int g = rowidx[m0 + ml];
            if (g >= 0) {
                size_t orow = (size_t)g * D_SZ;
#pragma unroll
                for (int j = 0; j < 4; ++j) {
                    int n = n0 + j * 16 + l16;
                    out[orow + n] = acc[i][j][r] + b2[p * D_SZ + n];
                }
            }
        }
    }
}

// ---------------- launch ----------------

extern "C" void kernel_launch(void* const* d_in, const int* in_sizes, int n_in,
                              void* d_out, int out_size, void* d_ws, size_t ws_size,
                              hipStream_t stream) {
    const float* latents = (const float*)d_in[0];
    const float* actions = (const float*)d_in[1];
    const int*   pol     = (const int*)d_in[2];
    const float* W1      = (const float*)d_in[3];
    const float* b1      = (const float*)d_in[4];
    const float* W2      = (const float*)d_in[5];
    const float* b2      = (const float*)d_in[6];
    float* out = (float*)d_out;

    char* ws = (char*)d_ws;
    int* counts    = (int*)ws;                   // 8
    int* cursors   = counts + P_SZ;              // 8
    int* blk_p     = cursors + P_SZ;             // MB_MAX
    int* blockhist = blk_p + MB_MAX;             // NSEG*P_SZ
    int* rowidx    = blockhist + NSEG * P_SZ;    // BPAD
    size_t pos = ((size_t)(2 * P_SZ + MB_MAX + NSEG * P_SZ + BPAD) * sizeof(int) + 255) & ~(size_t)255;
    bf16_t* xs  = (bf16_t*)(ws + pos);  pos += (size_t)BPAD * K1 * 2;
    bf16_t* hbuf= (bf16_t*)(ws + pos);  pos += (size_t)BPAD * H_SZ * 2;
    bf16_t* w1t = (bf16_t*)(ws + pos);  pos += (size_t)P_SZ * H_SZ * K1 * 2;
    bf16_t* w2t = (bf16_t*)(ws + pos);  pos += (size_t)P_SZ * D_SZ * H_SZ * 2;

    hist_block<<<NSEG, 256, 0, stream>>>(pol, blockhist, rowidx);
    prefix_kernel<<<1, 64, 0, stream>>>(blockhist, counts, cursors, blk_p);
    scatter_agg<<<NSEG, 256, 0, stream>>>(pol, cursors, rowidx);
    prep_x<<<(BPAD * 72) / 256, 256, 0, stream>>>(latents, actions, rowidx, xs);
    transpose_w<<<dim3(32, 32, 16), 256, 0, stream>>>(W1, W2, w1t, w2t);
    gemm1_kernel<<<dim3(MB_MAX, H_SZ / 64), 64, 0, stream>>>(xs, w1t, b1, blk_p, hbuf);
    gemm2_kernel<<<dim3(MB_MAX, D_SZ / 64), 64, 0, stream>>>(hbuf, w2t, b2, blk_p, rowidx, out);
}